// Round 10
// baseline (231.799 us; speedup 1.0000x reference)
//
#include <hip/hip_runtime.h>

// Pre-emphasis IIR: out[t] = y[t] + 0.85*out[t-1], shift SKIP=91, scale 32768,
// clip, astype(int16) (trunc toward zero); harness reads d_out as int32.
//
// R14 -> R15: R14 (asm-reg batch + counted vmcnt) FAILED correctness: the RA
// inserts copies/spills of asm destination VGPRs whose data hasn't landed
// (compiler models asm outputs as ready instantly; sched_barrier doesn't
// bind RA). Retroactively explains R12's null: reg-batch MLP has never
// actually executed. R15 gets guaranteed 9-deep MLP via
// __builtin_amdgcn_global_load_lds: NO destination register -> nothing to
// sink, nothing for RA to copy; LDS-DMA->ds_read hazard is backend-modeled.
// Per wave: 9 windows = one contiguous 9KB region sig[segBase-164,+2304) ->
// 9 back-to-back LDS-DMA loads -> one vmcnt(0)+sched_barrier (m97 pattern)
// -> ds_read_b128 -> R13's verified scan math. Wave-private LDS, ZERO
// barriers. 36KB/block -> 4 blk/CU, 16 waves/CU, ~43KB/CU avg in flight.

#define BLOCK   256
#define SKIP    91
#define COEF    0.85f
#define CHUNK_N 256                   // 64 lanes x 4 floats
#define CHUNKS  8                     // output windows per wave
#define SEG     (CHUNKS * CHUNK_N)    // 2048 outputs per wave
#define WPB     (BLOCK / 64)          // 4 waves per block
#define TILE    (WPB * SEG)           // 8192 outputs per block
#define NW      9                     // staged windows (warm + 8 main)
#define WFLOATS (NW * CHUNK_N)        // 2304 floats (9 KB) per wave

typedef int v4i __attribute__((ext_vector_type(4)));
typedef __attribute__((address_space(3))) void       as3_void;
typedef const __attribute__((address_space(1))) void as1_void;

__device__ __forceinline__ int cvt16(float v) {
    float s = v * 32768.f;
    s = fminf(fmaxf(s, -32768.f), 32767.f);   // v_med3_f32
    return (int)s;                            // trunc toward zero
}

__device__ __forceinline__ float chain4(const float4& v) {
    float a1 = fmaf(v.x, COEF, v.y);
    float a2 = fmaf(a1, COEF, v.z);
    return fmaf(a2, COEF, v.w);
}

template <int N>
__device__ __forceinline__ void wscan_multi(float (&t)[N], int lane) {
    const float K1  = COEF * COEF * COEF * COEF;    // c^4
    const float K2  = K1 * K1, K4 = K2 * K2, K8 = K4 * K4, K16 = K8 * K8;
    const float KS[5] = {K1, K2, K4, K8, K16};      // c^128 step ~9e-10: dropped
#pragma unroll
    for (int d = 0; d < 5; ++d) {
        const int sh = 1 << d;
        float u[N];
#pragma unroll
        for (int c = 0; c < N; ++c) u[c] = __shfl_up(t[c], sh, 64);
#pragma unroll
        for (int c = 0; c < N; ++c)
            t[c] = (lane >= sh) ? fmaf(u[c], KS[d], t[c]) : t[c];
    }
}

// ---- guarded (edge) path: per-element bounds, R13 logic (verified) ----
__device__ __forceinline__ float4 ld_guard(const float* __restrict__ sig,
                                           long yb, long n) {
    float4 x;
    x.x = (yb + 0 >= 0 && yb + 0 < n) ? sig[yb + 0] : 0.f;
    x.y = (yb + 1 >= 0 && yb + 1 < n) ? sig[yb + 1] : 0.f;
    x.z = (yb + 2 >= 0 && yb + 2 < n) ? sig[yb + 2] : 0.f;
    x.w = (yb + 3 >= 0 && yb + 3 < n) ? sig[yb + 3] : 0.f;
    return x;
}

__device__ void run_guard(const float* __restrict__ sig, int* __restrict__ out,
                          long segBase, long ln, int lane, float wq) {
    const float C1 = COEF, C2 = COEF * COEF, C3 = C2 * COEF;
    float4 x[9];
#pragma unroll
    for (int c = 0; c < 8; ++c)
        x[c] = ld_guard(sig, segBase + (SKIP + 1) + (long)c * CHUNK_N
                             + 4 * (long)lane, ln);
    x[8] = ld_guard(sig, segBase - 164 + 4 * (long)lane, ln);
    float t[9];
#pragma unroll
    for (int c = 0; c < 9; ++c) t[c] = chain4(x[c]);
    wscan_multi<9>(t, lane);
    float tsh[8], Tp[8];
#pragma unroll
    for (int c = 0; c < 8; ++c) tsh[c] = __shfl_up(t[c], 1, 64);
#pragma unroll
    for (int c = 0; c < 8; ++c) Tp[c] = __shfl(t[c == 0 ? 8 : c - 1], 63, 64);
    const long oLim = ln - SKIP;
#pragma unroll
    for (int c = 0; c < 8; ++c) {
        float u  = (lane == 0) ? 0.f : tsh[c];
        float p  = fmaf(Tp[c], wq, u);
        float s1 = fmaf(x[c].x, COEF, x[c].y);
        float s2 = fmaf(s1, COEF, x[c].z);
        v4i iv;
        iv.x = cvt16(p);
        iv.y = cvt16(fmaf(p, C1, x[c].x));
        iv.z = cvt16(fmaf(p, C2, s1));
        iv.w = cvt16(fmaf(p, C3, s2));
        const long ob = segBase + (long)c * CHUNK_N + 4 * (long)lane;
        if (ob + 0 >= oLim) iv.x = 0;
        if (ob + 1 >= oLim) iv.y = 0;
        if (ob + 2 >= oLim) iv.z = 0;
        if (ob + 3 >= oLim) iv.w = 0;
        if (ob + 0 < ln) out[ob + 0] = iv.x;
        if (ob + 1 < ln) out[ob + 1] = iv.y;
        if (ob + 2 < ln) out[ob + 2] = iv.z;
        if (ob + 3 < ln) out[ob + 3] = iv.w;
    }
}

__global__ __launch_bounds__(BLOCK, 4) void preemph_kernel(
        const float* __restrict__ sig, int* __restrict__ out, int n) {
    __shared__ float lds[WPB][WFLOATS];     // 36864 B: wave-private regions
    const long ln   = n;
    const int  lane = threadIdx.x & 63;
    const int  wid  = threadIdx.x >> 6;
    const long segBase = (long)blockIdx.x * TILE + (long)wid * SEG;
    if (segBase >= ln) return;

    // c^(4*lane): prev-lane carry weight (lane 0 -> 1.0)
    const float wq = exp2f((float)lane * (4.0f * -0.23446525109f)); // log2(0.85)

    const bool fast = (segBase >= 164) && (segBase + SEG + SKIP + 1 <= ln);
    if (!fast) { run_guard(sig, out, segBase, ln, lane, wq); return; }

    // ---- stage: 9 contiguous windows via LDS-DMA, no dest registers.
    // window w covers y[segBase-164 + w*256, +256): w=0 warm, w-1 = out chunk.
    // HW writes lane i at (uniform dest) + 16*i == gsrc lane layout exactly.
    const float* gsrc = sig + (segBase - 164) + 4 * (long)lane;
    float* lb = &lds[wid][0];
#pragma unroll
    for (int w = 0; w < NW; ++w)
        __builtin_amdgcn_global_load_lds((as1_void*)(gsrc + w * CHUNK_N),
                                         (as3_void*)(lb + w * CHUNK_N),
                                         16, 0, 0);
    // m97-verified gate: drain, then fence consumers below the drain.
    asm volatile("s_waitcnt vmcnt(0)" ::: "memory");
    __builtin_amdgcn_sched_barrier(0);

    // ---- read back own 16B per window (contiguous across lanes: conflict-free)
    float4 xw[NW];
    const float* lr = lb + 4 * lane;
#pragma unroll
    for (int w = 0; w < NW; ++w)
        xw[w] = *reinterpret_cast<const float4*>(lr + w * CHUNK_N);

    // ---- R13's verified scan: 9 independent windows, step-interleaved.
    float t[NW];
#pragma unroll
    for (int w = 0; w < NW; ++w) t[w] = chain4(xw[w]);
    wscan_multi<NW>(t, lane);

    // ---- outputs: chunk c uses window c+1; carry = window c's total
    // (inter-window chain weight c^256 ~ 8.6e-19: windows independent).
    const float C1 = COEF, C2 = COEF * COEF, C3 = C2 * COEF;
#pragma unroll
    for (int c = 0; c < CHUNKS; ++c) {
        float tsh = __shfl_up(t[c + 1], 1, 64);
        float Tp  = __shfl(t[c], 63, 64);
        float u   = (lane == 0) ? 0.f : tsh;
        float p   = fmaf(Tp, wq, u);        // full value at prev-lane elem3
        const float4 x = xw[c + 1];
        float s1 = fmaf(x.x, COEF, x.y);
        float s2 = fmaf(s1, COEF, x.z);
        v4i iv;                             // realigned by SKIP%4=3
        iv.x = cvt16(p);
        iv.y = cvt16(fmaf(p, C1, x.x));
        iv.z = cvt16(fmaf(p, C2, s1));
        iv.w = cvt16(fmaf(p, C3, s2));
        *reinterpret_cast<v4i*>(out + segBase + c * CHUNK_N + 4 * (long)lane) = iv;
    }
}

extern "C" void kernel_launch(void* const* d_in, const int* in_sizes, int n_in,
                              void* d_out, int out_size, void* d_ws, size_t ws_size,
                              hipStream_t stream) {
    const float* sig = (const float*)d_in[0];
    int* out = (int*)d_out;
    int n = in_sizes[0];
    int grid = (int)(((long)n + TILE - 1) / TILE);
    preemph_kernel<<<grid, BLOCK, 0, stream>>>(sig, out, n);
}